// Round 6
// baseline (601.424 us; speedup 1.0000x reference)
//
#include <hip/hip_runtime.h>

typedef __attribute__((ext_vector_type(4))) float f32x4;
typedef __attribute__((ext_vector_type(8))) short s16x8;
typedef __attribute__((ext_vector_type(4))) unsigned short u16x4;

__device__ __forceinline__ unsigned short f2bf(float f) {
    union { float f; unsigned int u; } v; v.f = f;
    unsigned int r = v.u + 0x7fffu + ((v.u >> 16) & 1u);
    return (unsigned short)(r >> 16);
}
// byte offset into a [48][256] bf16 LDS tile, XOR-swizzled (row stride 512B)
__device__ __forceinline__ unsigned int swz(int row, int col) {
    return (unsigned int)(row * 512 + col * 2) ^ (((unsigned int)row & 7u) << 4);
}
// byte offset into a [28][256] f32 LDS tile, XOR-swizzled (row stride 1024B)
__device__ __forceinline__ unsigned int swz32(int row, int col) {
    return (unsigned int)(row * 1024 + col * 4) ^ (((unsigned int)row & 7u) << 4);
}

// Weights pre-packed in MFMA B-fragment order:
// wt2[m][ct][kt][lane][e] = bf16(W_m[kt*32 + (lane>>4)*8 + e][ct*16 + (lane&15)])
__global__ void prep_w(const float* __restrict__ wq, const float* __restrict__ wk,
                       const float* __restrict__ wv, const float* __restrict__ wo,
                       unsigned short* __restrict__ wt2) {
    int idx = blockIdx.x * 256 + threadIdx.x;   // 0..32767
    int lane = idx & 63;
    int kt   = (idx >> 6) & 7;
    int nt   = (idx >> 9) & 15;
    int m    = idx >> 13;
    const float* W = (m == 0) ? wq : (m == 1) ? wk : (m == 2) ? wv : wo;
    int g = lane & 15, uu = lane >> 4;
    int n = nt * 16 + g;
    unsigned short* dst = wt2 + (size_t)idx * 8;
    #pragma unroll
    for (int e = 0; e < 8; ++e) {
        int k = kt * 32 + uu * 8 + e;
        dst[e] = f2bf(W[k * 256 + n]);
    }
}

__global__ __launch_bounds__(256, 2)
void fused_attn(const float* __restrict__ br0, const float* __restrict__ br1,
                const float* __restrict__ br2, const unsigned short* __restrict__ wt2,
                const float* __restrict__ bq, const float* __restrict__ bk,
                const float* __restrict__ bv, const float* __restrict__ bo,
                float* __restrict__ out) {
    // Xs double buffer (24 KB each) + Ys f32 (28 KB) = 76 KB -> 2 blocks/CU.
    __shared__ char ldsb[77824];
    char* Ys = ldsb + 49152;

    const int t    = threadIdx.x;
    const int wave = t >> 6;            // = head index
    const int lane = t & 63;
    const int g    = lane & 15;
    const int u    = lane >> 4;
    const int b    = blockIdx.x >> 6;   // 512 blocks: 64 per batch
    const int tb   = (blockIdx.x & 63) << 2;   // first tile (of 16 rows) of this block
    const int nb   = wave * 64;         // head column base
    const int cc   = lane * 4;

    const s16x8* WF = (const s16x8*)wt2;

    // hoisted biases (per wave column slice)
    float Bq[4], Bk[4], Bv[4], Bo[4];
    #pragma unroll
    for (int tc = 0; tc < 4; ++tc) {
        int col = nb + tc * 16 + g;
        Bq[tc] = bq[col]; Bk[tc] = bk[col]; Bv[tc] = bv[col]; Bo[tc] = bo[col];
    }

    // ---- staging registers for one tile (issued early, written to LDS late) ----
    f32x4 s0[4];            // br0 rows (no interp)
    f32x4 s1a[4], s1b[4];   // br1 row pairs
    f32x4 s2a[4], s2b[4];   // br2 row pairs

    auto issue = [&](int lt) {          // global loads for tile lt -> registers
        int l0 = lt << 4;
        #pragma unroll
        for (int it = 0; it < 4; ++it) {
            int l = l0 + it * 4 + wave;
            s0[it] = *(const f32x4*)(br0 + (size_t)(b * 4096 + l) * 256 + cc);
        }
        #pragma unroll
        for (int it = 0; it < 4; ++it) {
            int l = l0 + it * 4 + wave;
            float sp = fminf(fmaxf((l + 0.5f) * 0.5f - 0.5f, 0.0f), 2047.0f);
            int i0 = (int)sp;
            int i1 = min(i0 + 1, 2047);
            s1a[it] = *(const f32x4*)(br1 + (size_t)(b * 2048 + i0) * 256 + cc);
            s1b[it] = *(const f32x4*)(br1 + (size_t)(b * 2048 + i1) * 256 + cc);
        }
        #pragma unroll
        for (int it = 0; it < 4; ++it) {
            int l = l0 + it * 4 + wave;
            float sp = fminf(fmaxf((l + 0.5f) * 0.25f - 0.5f, 0.0f), 1023.0f);
            int i0 = (int)sp;
            int i1 = min(i0 + 1, 1023);
            s2a[it] = *(const f32x4*)(br2 + (size_t)(b * 1024 + i0) * 256 + cc);
            s2b[it] = *(const f32x4*)(br2 + (size_t)(b * 1024 + i1) * 256 + cc);
        }
    };
    auto writeX = [&](int lt, char* Xn) {   // interp + bf16 + swizzled LDS write
        int l0 = lt << 4;
        #pragma unroll
        for (int it = 0; it < 4; ++it) {
            int r = it * 4 + wave;
            u16x4 h;
            h.x = f2bf(s0[it].x); h.y = f2bf(s0[it].y);
            h.z = f2bf(s0[it].z); h.w = f2bf(s0[it].w);
            *(u16x4*)(Xn + swz(r, cc)) = h;
        }
        #pragma unroll
        for (int it = 0; it < 4; ++it) {
            int p = it * 4 + wave;
            int l = l0 + p;
            float sp = fminf(fmaxf((l + 0.5f) * 0.5f - 0.5f, 0.0f), 2047.0f);
            float w = sp - floorf(sp);
            f32x4 v = s1a[it] * (1.0f - w) + s1b[it] * w;
            u16x4 h;
            h.x = f2bf(v.x); h.y = f2bf(v.y); h.z = f2bf(v.z); h.w = f2bf(v.w);
            *(u16x4*)(Xn + swz(16 + p, cc)) = h;
        }
        #pragma unroll
        for (int it = 0; it < 4; ++it) {
            int p = it * 4 + wave;
            int l = l0 + p;
            float sp = fminf(fmaxf((l + 0.5f) * 0.25f - 0.5f, 0.0f), 1023.0f);
            float w = sp - floorf(sp);
            f32x4 v = s2a[it] * (1.0f - w) + s2b[it] * w;
            u16x4 h;
            h.x = f2bf(v.x); h.y = f2bf(v.y); h.z = f2bf(v.z); h.w = f2bf(v.w);
            *(u16x4*)(Xn + swz(32 + p, cc)) = h;
        }
    };

    // ---------------- prologue: stage tile 0 ----------------
    issue(tb);
    writeX(tb, ldsb);
    __syncthreads();

    #pragma unroll 1
    for (int il = 0; il < 4; ++il) {
        char* Xc = ldsb + ((il & 1) ? 24576 : 0);
        char* Xn = ldsb + ((il & 1) ? 0 : 24576);
        const int lt = tb + il;
        const int l0 = lt << 4;

        if (il < 3) issue(lt + 1);      // next tile's HBM loads in flight under compute

        // ------- fused Q+K+V projection + 3x3 scores + softmax (one X pass) -------
        float aw[4][3][3];
        f32x4 vacc[3][4];
        {
            float sc[3][3][4];
            #pragma unroll
            for (int n = 0; n < 3; ++n) {
                #pragma unroll
                for (int m = 0; m < 3; ++m)
                    #pragma unroll
                    for (int j = 0; j < 4; ++j) sc[n][m][j] = 0.f;
                #pragma unroll
                for (int tc = 0; tc < 4; ++tc)
                    vacc[n][tc] = (f32x4){0.f, 0.f, 0.f, 0.f};
            }
            #pragma unroll
            for (int tc = 0; tc < 4; ++tc) {
                const int ct = wave * 4 + tc;
                f32x4 qc[3], kc[3];
                #pragma unroll
                for (int n = 0; n < 3; ++n) {
                    qc[n] = (f32x4){0.f, 0.f, 0.f, 0.f};
                    kc[n] = (f32x4){0.f, 0.f, 0.f, 0.f};
                }
                #pragma unroll
                for (int kt = 0; kt < 8; ++kt) {
                    s16x8 bfq = WF[((0 * 16 + ct) * 8 + kt) * 64 + lane];
                    s16x8 bfk = WF[((1 * 16 + ct) * 8 + kt) * 64 + lane];
                    s16x8 bfv = WF[((2 * 16 + ct) * 8 + kt) * 64 + lane];
                    #pragma unroll
                    for (int n = 0; n < 3; ++n) {
                        s16x8 a = *(const s16x8*)(Xc + swz(n * 16 + g, kt * 32 + u * 8));
                        qc[n]       = __builtin_amdgcn_mfma_f32_16x16x32_bf16(a, bfq, qc[n], 0, 0, 0);
                        kc[n]       = __builtin_amdgcn_mfma_f32_16x16x32_bf16(a, bfk, kc[n], 0, 0, 0);
                        vacc[n][tc] = __builtin_amdgcn_mfma_f32_16x16x32_bf16(a, bfv, vacc[n][tc], 0, 0, 0);
                    }
                }
                #pragma unroll
                for (int n = 0; n < 3; ++n)
                    #pragma unroll
                    for (int j = 0; j < 4; ++j) {
                        qc[n][j] += Bq[tc];
                        kc[n][j] += Bk[tc];
                    }
                #pragma unroll
                for (int n = 0; n < 3; ++n)
                    #pragma unroll
                    for (int m = 0; m < 3; ++m)
                        #pragma unroll
                        for (int j = 0; j < 4; ++j)
                            sc[n][m][j] += qc[n][j] * kc[m][j];
            }
            #pragma unroll
            for (int mask = 1; mask < 16; mask <<= 1)
                #pragma unroll
                for (int n = 0; n < 3; ++n)
                    #pragma unroll
                    for (int m = 0; m < 3; ++m)
                        #pragma unroll
                        for (int j = 0; j < 4; ++j)
                            sc[n][m][j] += __shfl_xor(sc[n][m][j], mask, 16);
            #pragma unroll
            for (int n = 0; n < 3; ++n)
                #pragma unroll
                for (int j = 0; j < 4; ++j) {
                    float s0v = sc[n][0][j] * 0.125f;
                    float s1v = sc[n][1][j] * 0.125f;
                    float s2v = sc[n][2][j] * 0.125f;
                    float mx = fmaxf(s0v, fmaxf(s1v, s2v));
                    float e0 = __expf(s0v - mx), e1 = __expf(s1v - mx), e2 = __expf(s2v - mx);
                    float inv = 1.0f / (e0 + e1 + e2);
                    aw[j][n][0] = e0 * inv; aw[j][n][1] = e1 * inv; aw[j][n][2] = e2 * inv;
                }
            #pragma unroll
            for (int tc = 0; tc < 4; ++tc)
                #pragma unroll
                for (int n = 0; n < 3; ++n)
                    #pragma unroll
                    for (int j = 0; j < 4; ++j)
                        vacc[n][tc][j] += Bv[tc];
        }
        __syncthreads();    // B2: all X reads done before O overwrites Xc

        // ------- O = attn @ V (per-lane), bf16 into Xc -------
        #pragma unroll
        for (int n = 0; n < 3; ++n)
            #pragma unroll
            for (int tc = 0; tc < 4; ++tc)
                #pragma unroll
                for (int j = 0; j < 4; ++j) {
                    float o = aw[j][n][0] * vacc[0][tc][j] +
                              aw[j][n][1] * vacc[1][tc][j] +
                              aw[j][n][2] * vacc[2][tc][j];
                    *(unsigned short*)(Xc + swz(n * 16 + u * 4 + j, nb + tc * 16 + g)) = f2bf(o);
                }
        __syncthreads();    // B3: O complete before cross-head reads

        // ------- output projection (k-outer) -------
        f32x4 yacc[3][4];
        #pragma unroll
        for (int n = 0; n < 3; ++n)
            #pragma unroll
            for (int tc = 0; tc < 4; ++tc)
                yacc[n][tc] = (f32x4){0.f, 0.f, 0.f, 0.f};
        #pragma unroll
        for (int kt = 0; kt < 8; ++kt) {
            s16x8 af[3];
            #pragma unroll
            for (int n = 0; n < 3; ++n)
                af[n] = *(const s16x8*)(Xc + swz(n * 16 + g, kt * 32 + u * 8));
            #pragma unroll
            for (int tc = 0; tc < 4; ++tc) {
                s16x8 bfo = WF[((3 * 16 + wave * 4 + tc) * 8 + kt) * 64 + lane];
                #pragma unroll
                for (int n = 0; n < 3; ++n)
                    yacc[n][tc] = __builtin_amdgcn_mfma_f32_16x16x32_bf16(af[n], bfo, yacc[n][tc], 0, 0, 0);
            }
        }

        if (il < 3) writeX(lt + 1, Xn);     // staged tile -> other X buffer

        // ------- stage Y (bias + down-interp) into LDS f32 -------
        #pragma unroll
        for (int tc = 0; tc < 4; ++tc) {
            int col = nb + tc * 16 + g;
            #pragma unroll
            for (int j = 0; j < 4; ++j)
                *(float*)(Ys + swz32(u * 4 + j, col)) = yacc[0][tc][j] + Bo[tc];
            #pragma unroll
            for (int jj = 0; jj < 2; ++jj)
                *(float*)(Ys + swz32(16 + u * 2 + jj, col)) =
                    0.5f * (yacc[1][tc][2 * jj] + yacc[1][tc][2 * jj + 1]) + Bo[tc];
            *(float*)(Ys + swz32(24 + u, col)) =
                0.5f * (yacc[2][tc][1] + yacc[2][tc][2]) + Bo[tc];
        }
        __syncthreads();    // B4: Ys ready + Xn staged

        // ------- coalesced f32x4 stores -------
        #pragma unroll
        for (int it = 0; it < 4; ++it) {
            int r = it * 4 + wave;
            f32x4 v = *(const f32x4*)(Ys + swz32(r, cc));
            *(f32x4*)(out + (size_t)(b * 4096 + l0 + r) * 256 + cc) = v;
        }
        #pragma unroll
        for (int it = 0; it < 2; ++it) {
            int q = it * 4 + wave;
            f32x4 v = *(const f32x4*)(Ys + swz32(16 + q, cc));
            *(f32x4*)(out + 8388608 + (size_t)(b * 2048 + (l0 >> 1) + q) * 256 + cc) = v;
        }
        {
            f32x4 v = *(const f32x4*)(Ys + swz32(24 + wave, cc));
            *(f32x4*)(out + 12582912 + (size_t)(b * 1024 + (l0 >> 2) + wave) * 256 + cc) = v;
        }
        // next iteration's Ys writes are ordered after these reads by B2/B3 of il+1
    }
}

extern "C" void kernel_launch(void* const* d_in, const int* in_sizes, int n_in,
                              void* d_out, int out_size, void* d_ws, size_t ws_size,
                              hipStream_t stream) {
    const float* br0 = (const float*)d_in[0];
    const float* br1 = (const float*)d_in[1];
    const float* br2 = (const float*)d_in[2];
    const float* Wq  = (const float*)d_in[3];
    const float* bq  = (const float*)d_in[4];
    const float* Wk  = (const float*)d_in[5];
    const float* bk  = (const float*)d_in[6];
    const float* Wv  = (const float*)d_in[7];
    const float* bv  = (const float*)d_in[8];
    const float* Wo  = (const float*)d_in[9];
    const float* bo  = (const float*)d_in[10];

    unsigned short* wt2 = (unsigned short*)d_ws;  // 4*256*256 bf16 = 512 KB, fragment order

    prep_w<<<128, 256, 0, stream>>>(Wq, Wk, Wv, Wo, wt2);
    fused_attn<<<512, 256, 0, stream>>>(br0, br1, br2, wt2, bq, bk, bv, bo,
                                        (float*)d_out);
}

// Round 7
// 571.481 us; speedup vs baseline: 1.0524x; 1.0524x over previous
//
#include <hip/hip_runtime.h>

typedef __attribute__((ext_vector_type(4))) float f32x4;
typedef __attribute__((ext_vector_type(8))) short s16x8;
typedef __attribute__((ext_vector_type(4))) unsigned short u16x4;

__device__ __forceinline__ unsigned short f2bf(float f) {
    union { float f; unsigned int u; } v; v.f = f;
    unsigned int r = v.u + 0x7fffu + ((v.u >> 16) & 1u);
    return (unsigned short)(r >> 16);
}
// byte offset into a [48][256] bf16 LDS tile, XOR-swizzled (row stride 512B)
__device__ __forceinline__ unsigned int swz(int row, int col) {
    return (unsigned int)(row * 512 + col * 2) ^ (((unsigned int)row & 7u) << 4);
}
// byte offset into a [28][256] f32 LDS tile, XOR-swizzled (row stride 1024B)
__device__ __forceinline__ unsigned int swz32(int row, int col) {
    return (unsigned int)(row * 1024 + col * 4) ^ (((unsigned int)row & 7u) << 4);
}
// async global->LDS, 16B per lane, zero VGPR staging
__device__ __forceinline__ void load_lds16(const float* g, char* l) {
    __builtin_amdgcn_global_load_lds(
        (const __attribute__((address_space(1))) unsigned int*)g,
        (__attribute__((address_space(3))) unsigned int*)l, 16, 0, 0);
}

// Weights pre-packed in MFMA B-fragment order:
// wt2[m][ct][kt][lane][e] = bf16(W_m[kt*32 + (lane>>4)*8 + e][ct*16 + (lane&15)])
__global__ void prep_w(const float* __restrict__ wq, const float* __restrict__ wk,
                       const float* __restrict__ wv, const float* __restrict__ wo,
                       unsigned short* __restrict__ wt2) {
    int idx = blockIdx.x * 256 + threadIdx.x;   // 0..32767
    int lane = idx & 63;
    int kt   = (idx >> 6) & 7;
    int nt   = (idx >> 9) & 15;
    int m    = idx >> 13;
    const float* W = (m == 0) ? wq : (m == 1) ? wk : (m == 2) ? wv : wo;
    int g = lane & 15, uu = lane >> 4;
    int n = nt * 16 + g;
    unsigned short* dst = wt2 + (size_t)idx * 8;
    #pragma unroll
    for (int e = 0; e < 8; ++e) {
        int k = kt * 32 + uu * 8 + e;
        dst[e] = f2bf(W[k * 256 + n]);
    }
}

__global__ __launch_bounds__(256, 2)
void fused_attn(const float* __restrict__ br0, const float* __restrict__ br1,
                const float* __restrict__ br2, const unsigned short* __restrict__ wt2,
                const float* __restrict__ bq, const float* __restrict__ bk,
                const float* __restrict__ bv, const float* __restrict__ bo,
                float* __restrict__ out) {
    // [0,24576): X bf16 [48][256] swz (also O). [0,28672): Ys f32 [28][256] swz32 (overlay).
    // [28672, 61440): RAW 32 rows x 1024 B (async-staged raw f32 source rows).
    __shared__ char ldsb[61440];
    char* Xs  = ldsb;
    char* Ys  = ldsb;
    char* RAW = ldsb + 28672;

    const int t    = threadIdx.x;
    const int wave = t >> 6;            // = head index
    const int lane = t & 63;
    const int g    = lane & 15;
    const int u    = lane >> 4;
    const int b    = blockIdx.x >> 6;   // 512 blocks: 64 per batch
    const int tb   = (blockIdx.x & 63) << 2;   // first 16-row tile of this block
    const int nb   = wave * 64;         // head column base
    const int cc   = lane * 4;          // float column base (16B per lane)

    const s16x8* WF = (const s16x8*)wt2;

    // hoisted biases (per wave column slice)
    float Bq[4], Bk[4], Bv[4], Bo[4];
    #pragma unroll
    for (int tc = 0; tc < 4; ++tc) {
        int col = nb + tc * 16 + g;
        Bq[tc] = bq[col]; Bk[tc] = bk[col]; Bv[tc] = bv[col]; Bo[tc] = bo[col];
    }

    // ---- async stage of one tile's 32 unique raw rows (8 global_load_lds per wave) ----
    // slots 0..15: br0 rows l0..l0+15 ; 16..25: br1 rows base1+0..9 ; 26..31: br2 base2+0..5
    auto stage = [&](int lt) {
        const int l0n = lt << 4;
        #pragma unroll
        for (int i = 0; i < 8; ++i) {
            int s = i * 4 + wave;       // wave-uniform slot
            const float* src;
            if (s < 16) {
                src = br0 + (size_t)(b * 4096 + l0n + s) * 256;
            } else if (s < 26) {
                int r = min(max(l0n / 2 - 1 + (s - 16), 0), 2047);
                src = br1 + (size_t)(b * 2048 + r) * 256;
            } else {
                int r = min(max(l0n / 4 - 1 + (s - 26), 0), 1023);
                src = br2 + (size_t)(b * 1024 + r) * 256;
            }
            load_lds16(src + cc, RAW + s * 1024);
        }
    };

    // ---- convert RAW -> X (interp in f32, cast bf16, swizzled write) ----
    auto convert = [&]() {
        #pragma unroll
        for (int it = 0; it < 12; ++it) {
            int r = it * 4 + wave;
            int p = r & 15;
            f32x4 v;
            if (r < 16) {
                v = *(const f32x4*)(RAW + r * 1024 + cc * 4);
            } else if (r < 32) {
                int o = 16 + ((p + (p & 1)) >> 1);
                float w = (p & 1) ? 0.25f : 0.75f;
                f32x4 a0 = *(const f32x4*)(RAW + o * 1024 + cc * 4);
                f32x4 a1 = *(const f32x4*)(RAW + (o + 1) * 1024 + cc * 4);
                v = a0 * (1.0f - w) + a1 * w;
            } else {
                int c = p & 3;
                int o = 26 + (p >> 2) + (c >> 1);
                float w = 0.125f + 0.25f * (float)((c + 2) & 3);
                f32x4 a0 = *(const f32x4*)(RAW + o * 1024 + cc * 4);
                f32x4 a1 = *(const f32x4*)(RAW + (o + 1) * 1024 + cc * 4);
                v = a0 * (1.0f - w) + a1 * w;
            }
            u16x4 h;
            h.x = f2bf(v.x); h.y = f2bf(v.y); h.z = f2bf(v.z); h.w = f2bf(v.w);
            *(u16x4*)(Xs + swz(r, cc)) = h;
        }
    };

    // ---------------- prologue: stage tile 0 ----------------
    stage(tb);
    __syncthreads();    // drains vmcnt -> RAW ready

    #pragma unroll 1
    for (int il = 0; il < 4; ++il) {
        const int lt = tb + il;
        const int l0 = lt << 4;

        convert();
        __syncthreads();            // B1: X ready, RAW free

        if (il < 3) stage(lt + 1);  // async loads in flight under QKV compute

        // ------- fused Q+K+V projection + 3x3 scores + softmax (one X pass) -------
        float aw[4][3][3];
        f32x4 vacc[3][4];
        {
            float sc[3][3][4];
            #pragma unroll
            for (int n = 0; n < 3; ++n) {
                #pragma unroll
                for (int m = 0; m < 3; ++m)
                    #pragma unroll
                    for (int j = 0; j < 4; ++j) sc[n][m][j] = 0.f;
                #pragma unroll
                for (int tc = 0; tc < 4; ++tc)
                    vacc[n][tc] = (f32x4){0.f, 0.f, 0.f, 0.f};
            }
            #pragma unroll
            for (int tc = 0; tc < 4; ++tc) {
                const int ct = wave * 4 + tc;
                f32x4 qc[3], kc[3];
                #pragma unroll
                for (int n = 0; n < 3; ++n) {
                    qc[n] = (f32x4){0.f, 0.f, 0.f, 0.f};
                    kc[n] = (f32x4){0.f, 0.f, 0.f, 0.f};
                }
                #pragma unroll
                for (int kt = 0; kt < 8; ++kt) {
                    s16x8 bfq = WF[((0 * 16 + ct) * 8 + kt) * 64 + lane];
                    s16x8 bfk = WF[((1 * 16 + ct) * 8 + kt) * 64 + lane];
                    s16x8 bfv = WF[((2 * 16 + ct) * 8 + kt) * 64 + lane];
                    #pragma unroll
                    for (int n = 0; n < 3; ++n) {
                        s16x8 a = *(const s16x8*)(Xs + swz(n * 16 + g, kt * 32 + u * 8));
                        qc[n]       = __builtin_amdgcn_mfma_f32_16x16x32_bf16(a, bfq, qc[n], 0, 0, 0);
                        kc[n]       = __builtin_amdgcn_mfma_f32_16x16x32_bf16(a, bfk, kc[n], 0, 0, 0);
                        vacc[n][tc] = __builtin_amdgcn_mfma_f32_16x16x32_bf16(a, bfv, vacc[n][tc], 0, 0, 0);
                    }
                }
                #pragma unroll
                for (int n = 0; n < 3; ++n)
                    #pragma unroll
                    for (int j = 0; j < 4; ++j) {
                        qc[n][j] += Bq[tc];
                        kc[n][j] += Bk[tc];
                    }
                #pragma unroll
                for (int n = 0; n < 3; ++n)
                    #pragma unroll
                    for (int m = 0; m < 3; ++m)
                        #pragma unroll
                        for (int j = 0; j < 4; ++j)
                            sc[n][m][j] += qc[n][j] * kc[m][j];
            }
            #pragma unroll
            for (int mask = 1; mask < 16; mask <<= 1)
                #pragma unroll
                for (int n = 0; n < 3; ++n)
                    #pragma unroll
                    for (int m = 0; m < 3; ++m)
                        #pragma unroll
                        for (int j = 0; j < 4; ++j)
                            sc[n][m][j] += __shfl_xor(sc[n][m][j], mask, 16);
            #pragma unroll
            for (int n = 0; n < 3; ++n)
                #pragma unroll
                for (int j = 0; j < 4; ++j) {
                    float s0v = sc[n][0][j] * 0.125f;
                    float s1v = sc[n][1][j] * 0.125f;
                    float s2v = sc[n][2][j] * 0.125f;
                    float mx = fmaxf(s0v, fmaxf(s1v, s2v));
                    float e0 = __expf(s0v - mx), e1 = __expf(s1v - mx), e2 = __expf(s2v - mx);
                    float inv = 1.0f / (e0 + e1 + e2);
                    aw[j][n][0] = e0 * inv; aw[j][n][1] = e1 * inv; aw[j][n][2] = e2 * inv;
                }
            #pragma unroll
            for (int tc = 0; tc < 4; ++tc)
                #pragma unroll
                for (int n = 0; n < 3; ++n)
                    #pragma unroll
                    for (int j = 0; j < 4; ++j)
                        vacc[n][tc][j] += Bv[tc];
        }
        __syncthreads();    // B2: X reads done (also drains stage loads into RAW)

        // ------- O = attn @ V (per-lane), bf16 into Xs -------
        #pragma unroll
        for (int n = 0; n < 3; ++n)
            #pragma unroll
            for (int tc = 0; tc < 4; ++tc)
                #pragma unroll
                for (int j = 0; j < 4; ++j) {
                    float o = aw[j][n][0] * vacc[0][tc][j] +
                              aw[j][n][1] * vacc[1][tc][j] +
                              aw[j][n][2] * vacc[2][tc][j];
                    *(unsigned short*)(Xs + swz(n * 16 + u * 4 + j, nb + tc * 16 + g)) = f2bf(o);
                }
        __syncthreads();    // B3: O complete before cross-head reads

        // ------- output projection (k-outer) -------
        f32x4 yacc[3][4];
        #pragma unroll
        for (int n = 0; n < 3; ++n)
            #pragma unroll
            for (int tc = 0; tc < 4; ++tc)
                yacc[n][tc] = (f32x4){0.f, 0.f, 0.f, 0.f};
        #pragma unroll
        for (int kt = 0; kt < 8; ++kt) {
            s16x8 af[3];
            #pragma unroll
            for (int n = 0; n < 3; ++n)
                af[n] = *(const s16x8*)(Xs + swz(n * 16 + g, kt * 32 + u * 8));
            #pragma unroll
            for (int tc = 0; tc < 4; ++tc) {
                s16x8 bfo = WF[((3 * 16 + wave * 4 + tc) * 8 + kt) * 64 + lane];
                #pragma unroll
                for (int n = 0; n < 3; ++n)
                    yacc[n][tc] = __builtin_amdgcn_mfma_f32_16x16x32_bf16(af[n], bfo, yacc[n][tc], 0, 0, 0);
            }
        }
        __syncthreads();    // B4: O reads done (Ys overlays the same LDS)

        // ------- stage Y (bias + down-interp) into LDS f32 -------
        #pragma unroll
        for (int tc = 0; tc < 4; ++tc) {
            int col = nb + tc * 16 + g;
            #pragma unroll
            for (int j = 0; j < 4; ++j)
                *(float*)(Ys + swz32(u * 4 + j, col)) = yacc[0][tc][j] + Bo[tc];
            #pragma unroll
            for (int jj = 0; jj < 2; ++jj)
                *(float*)(Ys + swz32(16 + u * 2 + jj, col)) =
                    0.5f * (yacc[1][tc][2 * jj] + yacc[1][tc][2 * jj + 1]) + Bo[tc];
            *(float*)(Ys + swz32(24 + u, col)) =
                0.5f * (yacc[2][tc][1] + yacc[2][tc][2]) + Bo[tc];
        }
        __syncthreads();    // B5: Ys ready

        // ------- coalesced f32x4 stores -------
        #pragma unroll
        for (int it = 0; it < 4; ++it) {
            int r = it * 4 + wave;
            f32x4 v = *(const f32x4*)(Ys + swz32(r, cc));
            *(f32x4*)(out + (size_t)(b * 4096 + l0 + r) * 256 + cc) = v;
        }
        #pragma unroll
        for (int it = 0; it < 2; ++it) {
            int q = it * 4 + wave;
            f32x4 v = *(const f32x4*)(Ys + swz32(16 + q, cc));
            *(f32x4*)(out + 8388608 + (size_t)(b * 2048 + (l0 >> 1) + q) * 256 + cc) = v;
        }
        {
            f32x4 v = *(const f32x4*)(Ys + swz32(24 + wave, cc));
            *(f32x4*)(out + 12582912 + (size_t)(b * 1024 + (l0 >> 2) + wave) * 256 + cc) = v;
        }
        __syncthreads();    // B6: Ys reads done before next convert overwrites X/Ys
    }
}

extern "C" void kernel_launch(void* const* d_in, const int* in_sizes, int n_in,
                              void* d_out, int out_size, void* d_ws, size_t ws_size,
                              hipStream_t stream) {
    const float* br0 = (const float*)d_in[0];
    const float* br1 = (const float*)d_in[1];
    const float* br2 = (const float*)d_in[2];
    const float* Wq  = (const float*)d_in[3];
    const float* bq  = (const float*)d_in[4];
    const float* Wk  = (const float*)d_in[5];
    const float* bk  = (const float*)d_in[6];
    const float* Wv  = (const float*)d_in[7];
    const float* bv  = (const float*)d_in[8];
    const float* Wo  = (const float*)d_in[9];
    const float* bo  = (const float*)d_in[10];

    unsigned short* wt2 = (unsigned short*)d_ws;  // 4*256*256 bf16 = 512 KB, fragment order

    prep_w<<<128, 256, 0, stream>>>(Wq, Wk, Wv, Wo, wt2);
    fused_attn<<<512, 256, 0, stream>>>(br0, br1, br2, wt2, bq, bk, bv, bo,
                                        (float*)d_out);
}